// Round 4
// baseline (2372.466 us; speedup 1.0000x reference)
//
#include <hip/hip_runtime.h>
#include <hip/hip_bf16.h>
#include <math.h>

#define MDIM 250
#define NDIM 250
#define DTOT 500          // M + N
#define HDIM 512
#define BATCH 1024
#define N_ITER 1000
#define OMEGA_C 1.8f
#define SIGMA_C 0.1f
#define TOL2 2.5e-9f      // (5e-5)^2 per-row ||ds||^2 early-exit threshold
#define KCACHE 120        // At rows cached in VGPRs (phase 1)
#define MCACHE 120        // AinvT rows cached in VGPRs (phase 2)

// ---------------------------------------------------------------------------
// Phase A kernels (one-time setup per call) — identical to R2 (proven fast)
// ---------------------------------------------------------------------------

// AinvT[m*500 + i] = Aaug_inv[i*250 + m]   (Aaug_inv is 500x250 row-major)
__global__ void transpose_kernel(const float* __restrict__ Ainv, float* __restrict__ AinvT) {
    int o = blockIdx.x * blockDim.x + threadIdx.x;
    if (o >= MDIM * DTOT) return;
    int m = o / DTOT;
    int i = o % DTOT;
    AinvT[o] = Ainv[i * MDIM + m];
}

// At[k*250 + m] = Aaug[m*500 + k]  for k,m < 250  (first 250 cols of Aaug = A)
__global__ void at_kernel(const float* __restrict__ Aaug, float* __restrict__ At) {
    int o = blockIdx.x * blockDim.x + threadIdx.x;
    if (o >= MDIM * MDIM) return;
    int k = o / MDIM;
    int m = o % MDIM;
    At[o] = Aaug[m * DTOT + k];
}

// x1 = relu([bv, cv] @ W1 + b1)
__global__ void mlp1_kernel(const float* __restrict__ b, const float* __restrict__ c,
                            const float* __restrict__ W1, const float* __restrict__ b1,
                            float* __restrict__ x1) {
    int r = blockIdx.x;
    int h = blockIdx.y * 256 + threadIdx.x;
    const float* xb = b + r * MDIM;
    const float* xc = c + r * NDIM;
    float acc = b1[h];
    #pragma unroll 5
    for (int k = 0; k < MDIM; ++k) acc += xb[k] * W1[k * HDIM + h];
    #pragma unroll 5
    for (int k = 0; k < NDIM; ++k) acc += xc[k] * W1[(k + MDIM) * HDIM + h];
    x1[r * HDIM + h] = fmaxf(acc, 0.0f);
}

// x2 = relu(x1 @ W2 + b2)
__global__ void mlp2_kernel(const float* __restrict__ x1, const float* __restrict__ W2,
                            const float* __restrict__ b2, float* __restrict__ x2) {
    int r = blockIdx.x;
    int h = blockIdx.y * 256 + threadIdx.x;
    const float* xr = x1 + r * HDIM;
    float acc = b2[h];
    #pragma unroll 8
    for (int k = 0; k < HDIM; ++k) acc += xr[k] * W2[k * HDIM + h];
    x2[r * HDIM + h] = fmaxf(acc, 0.0f);
}

// y = x2 @ W3 + b3
__global__ void mlp3_kernel(const float* __restrict__ x2, const float* __restrict__ W3,
                            const float* __restrict__ b3, float* __restrict__ y) {
    int r = blockIdx.x;
    int j = blockIdx.y * 256 + threadIdx.x;
    if (j >= DTOT) return;
    const float* xr = x2 + r * HDIM;
    float acc = b3[j];
    #pragma unroll 8
    for (int k = 0; k < HDIM; ++k) acc += xr[k] * W3[k * DTOT + j];
    y[r * DTOT + j] = acc;
}

// ---------------------------------------------------------------------------
// Phase B: persistent iteration kernel — R2 structure (256 blocks x 256 thr,
// 4 rows/block, 1 block/CU) with ONE change: the first KCACHE rows of At and
// MCACHE rows of AinvT are pinned in VGPRs (360 weight regs/thread = 330
// KB/CU), cutting per-CU L2 streaming 750 -> 390 KB/iter. At 1 wave/SIMD the
// VGPR budget is ~450/thread without spill (m08/m69), occupancy unchanged.
// ---------------------------------------------------------------------------
__global__ __launch_bounds__(256) void iterate_kernel(const float* __restrict__ At,
                                                      const float* __restrict__ AinvT,
                                                      const float* __restrict__ b,
                                                      const float* __restrict__ y,
                                                      float* __restrict__ out) {
    __shared__ __align__(16) float s4[DTOT * 4];    // s4[col*4 + row]
    __shared__ __align__(16) float w4[MDIM * 4];    // w4[m*4 + row]
    __shared__ __align__(16) float zbuf[4 * DTOT];  // zbuf[row*500 + col]
    __shared__ float dsum[4];

    const int t = threadIdx.x;
    const int row0 = blockIdx.x * 4;
    const float inv12 = 1.0f / (1.0f + 2.0f * SIGMA_C);
    const int er = t >> 6;
    const int el = t & 63;

    // per-thread constants in registers
    float bvr[4];
    #pragma unroll
    for (int r = 0; r < 4; ++r)
        bvr[r] = (t < MDIM) ? b[(row0 + r) * MDIM + t] : 0.0f;
    float yv[8];
    #pragma unroll
    for (int m = 0; m < 8; ++m) {
        int j = el + 64 * m;
        yv[m] = (j < DTOT) ? y[(row0 + er) * DTOT + j] : 0.0f;
    }

    // ---- register-pinned weights (one-time, coalesced) ----
    float  av[KCACHE];   // At[k*250 + t],            k < KCACHE
    float2 wv[MCACHE];   // AinvT[m*500 + 2t .. 2t+1], m < MCACHE
    {
        const float* ap = At + ((t < MDIM) ? t : 0);
        #pragma unroll
        for (int u = 0; u < KCACHE; ++u) av[u] = ap[u * MDIM];
        const float2* gp2 = (const float2*)AinvT + ((t < MDIM) ? t : 0);
        #pragma unroll
        for (int u = 0; u < MCACHE; ++u) wv[u] = gp2[u * MDIM];  // row stride = 250 float2
    }

    for (int e = t; e < 4 * DTOT; e += 256) s4[e] = 0.0f;
    __syncthreads();

    bool last = false;
    for (int it = 0; ; ++it) {
        // ---- phase 1: w_m = sum_k s_k At[k,m] + s_{250+m} - bv_m ----
        if (t < MDIM) {
            float4 sv = *(const float4*)(s4 + 4 * (MDIM + t));
            float4 acc;
            acc.x = sv.x - bvr[0]; acc.y = sv.y - bvr[1];
            acc.z = sv.z - bvr[2]; acc.w = sv.w - bvr[3];
            // cached k < KCACHE (weights in VGPRs, s broadcast from LDS)
            #pragma unroll
            for (int k = 0; k < KCACHE; ++k) {
                float4 sk = *(const float4*)(s4 + 4 * k);
                float g = av[k];
                acc.x += g * sk.x; acc.y += g * sk.y; acc.z += g * sk.z; acc.w += g * sk.w;
            }
            // streamed k = KCACHE..249 (130 values), R2 prefetch pattern
            const float* ap = At + t;
            float g0[10], g1[10];
            #pragma unroll
            for (int u = 0; u < 10; ++u) {
                g0[u] = ap[(KCACHE + u) * MDIM];
                g1[u] = ap[(KCACHE + 10 + u) * MDIM];
            }
            int kk = KCACHE;
            #pragma unroll 1
            for (int blk = 0; blk < 6; ++blk, kk += 20) {
                #pragma unroll
                for (int u = 0; u < 10; ++u) {
                    float g = g0[u];
                    g0[u] = ap[(kk + 20 + u) * MDIM];           // kk<=220 -> <=249, safe
                    float4 sk = *(const float4*)(s4 + 4 * (kk + u));
                    acc.x += g * sk.x; acc.y += g * sk.y; acc.z += g * sk.z; acc.w += g * sk.w;
                }
                #pragma unroll
                for (int u = 0; u < 10; ++u) {
                    float g = g1[u];
                    int kn = kk + 30 + u;
                    if (kn < MDIM) g1[u] = ap[kn * MDIM];
                    float4 sk = *(const float4*)(s4 + 4 * (kk + 10 + u));
                    acc.x += g * sk.x; acc.y += g * sk.y; acc.z += g * sk.z; acc.w += g * sk.w;
                }
            }
            #pragma unroll
            for (int u = 0; u < 10; ++u) {                      // kk = 240..249 from g0
                float g = g0[u];
                float4 sk = *(const float4*)(s4 + 4 * (240 + u));
                acc.x += g * sk.x; acc.y += g * sk.y; acc.z += g * sk.z; acc.w += g * sk.w;
            }
            *(float4*)(w4 + 4 * t) = acc;
        }
        __syncthreads();

        // ---- phase 2: z_i = s_i - sum_m w_m AinvT[m,i]  (2 cols/thread) ----
        if (t < MDIM) {
            const int i0 = 2 * t;
            float4 c0 = *(const float4*)(s4 + 4 * i0);
            float4 c1 = *(const float4*)(s4 + 4 * (i0 + 1));
            float2 a0 = {c0.x, c1.x}, a1 = {c0.y, c1.y}, a2 = {c0.z, c1.z}, a3 = {c0.w, c1.w};
            // cached m < MCACHE (weights in VGPRs, w broadcast from LDS)
            #pragma unroll
            for (int m = 0; m < MCACHE; ++m) {
                float2 gv = wv[m];
                float4 wvv = *(const float4*)(w4 + 4 * m);
                a0.x -= gv.x * wvv.x; a0.y -= gv.y * wvv.x;
                a1.x -= gv.x * wvv.y; a1.y -= gv.y * wvv.y;
                a2.x -= gv.x * wvv.z; a2.y -= gv.y * wvv.z;
                a3.x -= gv.x * wvv.w; a3.y -= gv.y * wvv.w;
            }
            // streamed m = MCACHE..249 (130 rows), relative indices 0..129
            const float2* gp = (const float2*)AinvT + MCACHE * MDIM + t;
            float2 g0[10], g1[10];
            #pragma unroll
            for (int u = 0; u < 10; ++u) { g0[u] = gp[u * MDIM]; g1[u] = gp[(10 + u) * MDIM]; }
            int mm = 0;
            #pragma unroll 1
            for (int blk = 0; blk < 6; ++blk, mm += 20) {
                #pragma unroll
                for (int u = 0; u < 10; ++u) {
                    float2 gv = g0[u];
                    g0[u] = gp[(mm + 20 + u) * MDIM];           // mm<=100 -> rel <=129, safe
                    float4 wvv = *(const float4*)(w4 + 4 * (MCACHE + mm + u));
                    a0.x -= gv.x * wvv.x; a0.y -= gv.y * wvv.x;
                    a1.x -= gv.x * wvv.y; a1.y -= gv.y * wvv.y;
                    a2.x -= gv.x * wvv.z; a2.y -= gv.y * wvv.z;
                    a3.x -= gv.x * wvv.w; a3.y -= gv.y * wvv.w;
                }
                #pragma unroll
                for (int u = 0; u < 10; ++u) {
                    float2 gv = g1[u];
                    int mn = mm + 30 + u;
                    if (mn < MDIM - MCACHE) g1[u] = gp[mn * MDIM];
                    float4 wvv = *(const float4*)(w4 + 4 * (MCACHE + mm + 10 + u));
                    a0.x -= gv.x * wvv.x; a0.y -= gv.y * wvv.x;
                    a1.x -= gv.x * wvv.y; a1.y -= gv.y * wvv.y;
                    a2.x -= gv.x * wvv.z; a2.y -= gv.y * wvv.z;
                    a3.x -= gv.x * wvv.w; a3.y -= gv.y * wvv.w;
                }
            }
            #pragma unroll
            for (int u = 0; u < 10; ++u) {                      // rel 120..129 from g0
                float2 gv = g0[u];
                float4 wvv = *(const float4*)(w4 + 4 * (MCACHE + 120 + u));
                a0.x -= gv.x * wvv.x; a0.y -= gv.y * wvv.x;
                a1.x -= gv.x * wvv.y; a1.y -= gv.y * wvv.y;
                a2.x -= gv.x * wvv.z; a2.y -= gv.y * wvv.z;
                a3.x -= gv.x * wvv.w; a3.y -= gv.y * wvv.w;
            }
            if (last) {
                *(float2*)(out + (row0 + 0) * DTOT + i0) = a0;
                *(float2*)(out + (row0 + 1) * DTOT + i0) = a1;
                *(float2*)(out + (row0 + 2) * DTOT + i0) = a2;
                *(float2*)(out + (row0 + 3) * DTOT + i0) = a3;
            } else {
                *(float2*)(zbuf + 0 * DTOT + i0) = a0;
                *(float2*)(zbuf + 1 * DTOT + i0) = a1;
                *(float2*)(zbuf + 2 * DTOT + i0) = a2;
                *(float2*)(zbuf + 3 * DTOT + i0) = a3;
            }
        }
        if (last) return;
        __syncthreads();

        // ---- elementwise DR update: wave er owns row er (R2 verbatim) ----
        {
            float tpv[8], zv[8], sv[8];
            float sums = 0.0f, tval_reg = 0.0f, dsq = 0.0f;
            #pragma unroll
            for (int m = 0; m < 8; ++m) {
                int j = el + 64 * m;
                if (j < DTOT) {
                    float z = zbuf[er * DTOT + j];
                    float s = s4[j * 4 + er];
                    float tp = (2.0f * z - s - 2.0f * SIGMA_C * yv[m]) * inv12;
                    if (j < NDIM) {
                        float d = OMEGA_C * (tp - z);
                        s4[j * 4 + er] = s + d;
                        dsq += d * d;
                    } else {
                        tpv[m] = tp; zv[m] = z; sv[m] = s;
                        if (j < DTOT - 1) sums += tp * tp;
                        else tval_reg = tp;
                    }
                }
            }
            #pragma unroll
            for (int off = 32; off > 0; off >>= 1) sums += __shfl_xor(sums, off);
            float norm = sqrtf(sums);
            float tval = __shfl(tval_reg, 51);   // lane 51 holds j=499
            float fac = (tval + norm) * 0.5f / (norm + 1e-12f);
            bool keep = (norm <= tval);
            bool zero = (norm <= -tval);
            #pragma unroll
            for (int m = 0; m < 8; ++m) {
                int j = el + 64 * m;
                if (j >= NDIM && j < DTOT) {
                    float tk;
                    if (j < DTOT - 1) tk = keep ? tpv[m] : (zero ? 0.0f : fac * tpv[m]);
                    else              tk = keep ? tpv[m] : (zero ? 0.0f : (tval + norm) * 0.5f);
                    float d = OMEGA_C * (tk - zv[m]);
                    s4[j * 4 + er] = sv[m] + d;
                    dsq += d * d;
                }
            }
            #pragma unroll
            for (int off = 32; off > 0; off >>= 1) dsq += __shfl_xor(dsq, off);
            if (el == 0) dsum[er] = dsq;
        }
        __syncthreads();

        if (it >= N_ITER - 1 ||
            (dsum[0] < TOL2 && dsum[1] < TOL2 && dsum[2] < TOL2 && dsum[3] < TOL2))
            last = true;
    }
}

// ---------------------------------------------------------------------------
extern "C" void kernel_launch(void* const* d_in, const int* in_sizes, int n_in,
                              void* d_out, int out_size, void* d_ws, size_t ws_size,
                              hipStream_t stream) {
    const float* b    = (const float*)d_in[0];
    const float* c    = (const float*)d_in[1];
    const float* W1   = (const float*)d_in[2];
    const float* b1   = (const float*)d_in[3];
    const float* W2   = (const float*)d_in[4];
    const float* b2   = (const float*)d_in[5];
    const float* W3   = (const float*)d_in[6];
    const float* b3   = (const float*)d_in[7];
    const float* Aaug = (const float*)d_in[8];
    const float* Ainv = (const float*)d_in[9];
    float* out = (float*)d_out;

    float* ws = (float*)d_ws;
    float* AinvT = ws;                       // 250*500
    float* At    = AinvT + MDIM * DTOT;      // 250*250
    float* x1    = At + MDIM * MDIM;         // 1024*512
    float* x2    = x1 + BATCH * HDIM;        // 1024*512
    float* y     = x2 + BATCH * HDIM;        // 1024*500

    transpose_kernel<<<(MDIM * DTOT + 255) / 256, 256, 0, stream>>>(Ainv, AinvT);
    at_kernel<<<(MDIM * MDIM + 255) / 256, 256, 0, stream>>>(Aaug, At);
    mlp1_kernel<<<dim3(BATCH, 2), 256, 0, stream>>>(b, c, W1, b1, x1);
    mlp2_kernel<<<dim3(BATCH, 2), 256, 0, stream>>>(x1, W2, b2, x2);
    mlp3_kernel<<<dim3(BATCH, 2), 256, 0, stream>>>(x2, W3, b3, y);
    iterate_kernel<<<256, 256, 0, stream>>>(At, AinvT, b, y, out);
}